// Round 12
// baseline (135.636 us; speedup 1.0000x reference)
//
#include <hip/hip_runtime.h>
#include <math.h>

// Problem constants (from reference): B=64, T=2048, D=256
#define BB 64
#define TT 2048
#define D4 64             // D/4 -> one float4 per lane, one wave covers D
#define SS 128            // time segments (short: more p3 parallelism)
#define LL (TT / SS)      // 16 steps per segment
#define WPB 4             // waves per block (each wave owns one chain b)
#define BPG (BB / WPB)    // 16 b-groups; 16 % 8 == 0 -> column<->XCD affinity
#define GRID (SS * BPG)   // 2048 blocks

// Native clang vector: elementwise ops, NT-load/store compatible.
typedef float f4 __attribute__((ext_vector_type(4)));

// -------------------- math helpers --------------------

__device__ __forceinline__ float softplus_f(float x) {
    // stable log1p(exp(x)) to match jax.nn.softplus
    return (x > 0.f) ? (x + log1pf(expf(-x))) : log1pf(expf(x));
}

struct P4 { f4 k, s2, r, mu; };   // per-lane params for 4 dims
struct C4 { f4 A, bm, sQ; };      // per-step coefficients
struct P1 { float k, s2, r; };
struct C1 { float A, bm, sQ; };

__device__ __forceinline__ P1 sp1(float lk, float ls) {
    P1 o;
    o.k = softplus_f(lk) + 1e-6f;
    float s = softplus_f(ls) + 1e-6f;
    o.s2 = s * s;
    o.r = o.s2 / fmaxf(2.f * o.k, 1e-12f);
    return o;
}

__device__ __forceinline__ P4 load_params4(const f4* __restrict__ mu4,
                                           const f4* __restrict__ lk4,
                                           const f4* __restrict__ ls4,
                                           int lane) {
    f4 lk = lk4[lane], ls = ls4[lane], mu = mu4[lane];
    P4 p;
    P1 a;
    a = sp1(lk.x, ls.x); p.k.x = a.k; p.s2.x = a.s2; p.r.x = a.r;
    a = sp1(lk.y, ls.y); p.k.y = a.k; p.s2.y = a.s2; p.r.y = a.r;
    a = sp1(lk.z, ls.z); p.k.z = a.k; p.s2.z = a.s2; p.r.z = a.r;
    a = sp1(lk.w, ls.w); p.k.w = a.k; p.s2.w = a.s2; p.r.w = a.r;
    p.mu = mu;
    return p;
}

// Exact OU transition coefficients (A = exp(-k dt); Q exact w/ Taylor fallback).
__device__ __forceinline__ C1 ou_coeff(float dt, float kappa, float s2, float r,
                                       float mu) {
    C1 o;
    float e = kappa * dt;
    o.A = __expf(-e);
    float two = 2.f * e;
    float Qe = r * (1.f - o.A * o.A);
    float Qt = s2 * dt * fmaf(two * two, (1.f / 6.f), 1.f - e);
    float Q = (two < 1e-6f) ? Qt : Qe;
    o.sQ = sqrtf(Q);
    o.bm = mu * (1.f - o.A);
    return o;
}

__device__ __forceinline__ C4 coeff4(float dt, const P4& p) {
    C4 c;
    C1 o;
    o = ou_coeff(dt, p.k.x, p.s2.x, p.r.x, p.mu.x); c.A.x = o.A; c.bm.x = o.bm; c.sQ.x = o.sQ;
    o = ou_coeff(dt, p.k.y, p.s2.y, p.r.y, p.mu.y); c.A.y = o.A; c.bm.y = o.bm; c.sQ.y = o.sQ;
    o = ou_coeff(dt, p.k.z, p.s2.z, p.r.z, p.mu.z); c.A.z = o.A; c.bm.z = o.bm; c.sQ.z = o.sQ;
    o = ou_coeff(dt, p.k.w, p.s2.w, p.r.w, p.mu.w); c.A.w = o.A; c.bm.w = o.bm; c.sQ.w = o.sQ;
    return c;
}

__device__ __forceinline__ f4 sqrt4(const f4 v) {
    f4 r;
    r.x = sqrtf(v.x); r.y = sqrtf(v.y); r.z = sqrtf(v.z); r.w = sqrtf(v.w);
    return r;
}

// -------------------- pass 1: segment partials (noise read #1) ------------
// Block (s,bg), wave w owns chain b = bg*4+w. NT-reads its noise segment,
// writes packed (P,U) ADJACENT in one f4 pair (same 128B line -> pass 2's
// scan costs one line per hop instead of two).
__global__ __launch_bounds__(256) void ou_partials(
    const float* __restrict__ ts, const f4* __restrict__ noise4,
    const f4* __restrict__ mu4, const f4* __restrict__ lk4,
    const f4* __restrict__ ls4,
    f4* __restrict__ PU) {
    __shared__ float dts[LL];
    const int lane = threadIdx.x & 63;
    const int w = threadIdx.x >> 6;
    const int s = blockIdx.x / BPG;
    const int bg = blockIdx.x % BPG;
    const int b = bg * WPB + w;
    const int t0 = s * LL;

    if (threadIdx.x < LL) {
        int k = t0 + threadIdx.x;
        float dt = 1e-6f;
        if (k >= 1) dt = fmaxf(ts[k] - ts[k - 1], 1e-6f);
        dts[threadIdx.x] = dt;
    }
    __syncthreads();

    P4 p = load_params4(mu4, lk4, ls4, lane);
    const f4* np = noise4 + (size_t)b * TT * D4 + lane;

    f4 U = {0.f, 0.f, 0.f, 0.f};
    f4 P = {1.f, 1.f, 1.f, 1.f};
    int kstart = t0;
    if (s == 0) {
        f4 n0 = __builtin_nontemporal_load(np);
        U = n0 * sqrt4(p.r) + p.mu;   // true initial condition
        P = (f4){0.f, 0.f, 0.f, 0.f}; // absorbing: U is the actual state
        kstart = 1;
    }

    float dtprev = -1.f;
    C4 cc;
#pragma unroll 4
    for (int k = kstart; k < t0 + LL; ++k) {
        float dt = dts[k - t0];
        f4 n = __builtin_nontemporal_load(np + (size_t)k * D4);
        if (dt != dtprev) { cc = coeff4(dt, p); dtprev = dt; } // wave-uniform
        f4 cv = cc.sQ * n + cc.bm;
        U = cc.A * U + cv;
        P *= cc.A;
    }

    // packed publish: P and U adjacent (one cache line)
    size_t base = (((size_t)s * BB + b) * D4 + lane) * 2;
    PU[base] = P;
    PU[base + 1] = U;
}

// -------------------- pass 2: per-block scan + replay (noise read #2) ------
// Block (s,bg) redundantly scans its columns' packed partials j=0..s-1
// (independent-address loads -> fully pipelined; only the fma chain is
// serial), then replays its segment and writes the output. Reversed-s:
// long-scan blocks dispatch first. No cross-block sync of any kind.
__global__ __launch_bounds__(256) void ou_scan_replay(
    const float* __restrict__ ts, const f4* __restrict__ noise4,
    const f4* __restrict__ mu4, const f4* __restrict__ lk4,
    const f4* __restrict__ ls4,
    const f4* __restrict__ PU, f4* __restrict__ out4) {
    __shared__ float dts[LL];
    const int lane = threadIdx.x & 63;
    const int w = threadIdx.x >> 6;
    const int s = (SS - 1) - (blockIdx.x / BPG);  // reversed: long scans first
    const int bg = blockIdx.x % BPG;
    const int b = bg * WPB + w;
    const int t0 = s * LL;

    if (threadIdx.x < LL) {
        int k = t0 + threadIdx.x;
        float dt = 1e-6f;
        if (k >= 1) dt = fmaxf(ts[k] - ts[k - 1], 1e-6f);
        dts[threadIdx.x] = dt;
    }
    __syncthreads();

    P4 p = load_params4(mu4, lk4, ls4, lane);
    const f4* np = noise4 + (size_t)b * TT * D4 + lane;
    f4* op = out4 + (size_t)b * TT * D4 + lane;

    f4 y;
    int kstart = t0;
    if (s == 0) {
        f4 n0 = __builtin_nontemporal_load(np);
        y = n0 * sqrt4(p.r) + p.mu;
        op[0] = y;
        kstart = 1;
    } else {
        // boundary scan over segments 0..s-1 (L2-resident packed PU;
        // segment 0's P=0 absorbs, so uniform inc = P*inc + U from inc=0)
        f4 inc = {0.f, 0.f, 0.f, 0.f};
        const size_t lbase = (size_t)b * D4 + lane;
        const size_t stride = (size_t)BB * D4;
#pragma unroll 4
        for (int j = 0; j < s; ++j) {
            size_t base = (lbase + (size_t)j * stride) * 2;
            f4 Pv = PU[base];
            f4 Uv = PU[base + 1];
            inc = Pv * inc + Uv;
        }
        y = inc; // y at end of segment s-1 == start state for segment s
    }

    float dtprev = -1.f;
    C4 cc;
#pragma unroll 4
    for (int k = kstart; k < t0 + LL; ++k) {
        float dt = dts[k - t0];
        f4 n = __builtin_nontemporal_load(np + (size_t)k * D4);
        if (dt != dtprev) { cc = coeff4(dt, p); dtprev = dt; } // wave-uniform
        f4 cv = cc.sQ * n + cc.bm;
        y = cc.A * y + cv;
        op[(size_t)k * D4] = y;   // plain store: L2 write-combined
    }
}

// -------------------- last-resort fallback: plain per-chain scan ------------
__global__ __launch_bounds__(128) void ou_fallback(
    const float* __restrict__ ts, const float2* __restrict__ noise2,
    const float2* __restrict__ mu2, const float2* __restrict__ lk2,
    const float2* __restrict__ ls2, float2* __restrict__ out2) {
    __shared__ float dts[TT];
    const int tid = threadIdx.x;
    const int b = blockIdx.x;
    for (int i = tid; i < TT; i += 128) {
        float dt = 1e-6f;
        if (i >= 1) dt = fmaxf(ts[i] - ts[i - 1], 1e-6f);
        dts[i] = dt;
    }
    __syncthreads();

    float2 lk = lk2[tid], ls = ls2[tid], mu = mu2[tid];
    P1 px = sp1(lk.x, ls.x);
    P1 py = sp1(lk.y, ls.y);

    const float2* np = noise2 + (size_t)b * TT * 128 + tid;
    float2* op = out2 + (size_t)b * TT * 128 + tid;

    float2 n0 = np[0];
    float2 y;
    y.x = fmaf(n0.x, sqrtf(px.r), mu.x);
    y.y = fmaf(n0.y, sqrtf(py.r), mu.y);
    op[0] = y;

#pragma unroll 4
    for (int k = 1; k < TT; ++k) {
        float dt = dts[k];
        float2 n = np[(size_t)k * 128];
        C1 cx = ou_coeff(dt, px.k, px.s2, px.r, mu.x);
        C1 cy = ou_coeff(dt, py.k, py.s2, py.r, mu.y);
        y.x = fmaf(cx.A, y.x, fmaf(cx.sQ, n.x, cx.bm));
        y.y = fmaf(cy.A, y.y, fmaf(cy.sQ, n.y, cy.bm));
        op[(size_t)k * 128] = y;
    }
}

// -------------------- launch --------------------
extern "C" void kernel_launch(void* const* d_in, const int* in_sizes, int n_in,
                              void* d_out, int out_size, void* d_ws, size_t ws_size,
                              hipStream_t stream) {
    const float* ts = (const float*)d_in[0];
    const f4* noise4 = (const f4*)d_in[1];
    const f4* mu4 = (const f4*)d_in[2];
    const f4* lk4 = (const f4*)d_in[3];
    const f4* ls4 = (const f4*)d_in[4];
    f4* out4 = (f4*)d_out;

    const size_t need = (size_t)SS * BB * D4 * 2 * sizeof(f4);   // 16.8 MB
    if (ws_size >= need) {
        f4* PU = (f4*)d_ws;
        ou_partials<<<GRID, 256, 0, stream>>>(ts, noise4, mu4, lk4, ls4, PU);
        ou_scan_replay<<<GRID, 256, 0, stream>>>(ts, noise4, mu4, lk4, ls4,
                                                 PU, out4);
    } else {
        ou_fallback<<<BB, 128, 0, stream>>>(ts, (const float2*)d_in[1],
                                            (const float2*)d_in[2],
                                            (const float2*)d_in[3],
                                            (const float2*)d_in[4],
                                            (float2*)d_out);
    }
}

// Round 13
// 110.150 us; speedup vs baseline: 1.2314x; 1.2314x over previous
//
#include <hip/hip_runtime.h>
#include <math.h>

// Problem constants (from reference): B=64, T=2048, D=256
#define BB 64
#define TT 2048
#define D4 64             // D/4 -> one float4 per lane, one wave covers D
#define SS 64             // time segments (64: scan O(SS^2) stays cheap, r12)
#define LL (TT / SS)      // 32 steps per segment
#define WPB 4             // waves per block (each wave owns one chain b)
#define BPG (BB / WPB)    // 16 b-groups
#define GRID (SS * BPG)   // 1024 blocks
#define PF 8              // noise f4 prefetch depth in pass 2

// Native clang vector: elementwise ops, NT-load/store compatible.
typedef float f4 __attribute__((ext_vector_type(4)));

// -------------------- math helpers --------------------

__device__ __forceinline__ float softplus_f(float x) {
    // stable log1p(exp(x)) to match jax.nn.softplus
    return (x > 0.f) ? (x + log1pf(expf(-x))) : log1pf(expf(x));
}

struct P4 { f4 k, s2, r, mu; };   // per-lane params for 4 dims
struct C4 { f4 A, bm, sQ; };      // per-step coefficients
struct P1 { float k, s2, r; };
struct C1 { float A, bm, sQ; };

__device__ __forceinline__ P1 sp1(float lk, float ls) {
    P1 o;
    o.k = softplus_f(lk) + 1e-6f;
    float s = softplus_f(ls) + 1e-6f;
    o.s2 = s * s;
    o.r = o.s2 / fmaxf(2.f * o.k, 1e-12f);
    return o;
}

__device__ __forceinline__ P4 load_params4(const f4* __restrict__ mu4,
                                           const f4* __restrict__ lk4,
                                           const f4* __restrict__ ls4,
                                           int lane) {
    f4 lk = lk4[lane], ls = ls4[lane], mu = mu4[lane];
    P4 p;
    P1 a;
    a = sp1(lk.x, ls.x); p.k.x = a.k; p.s2.x = a.s2; p.r.x = a.r;
    a = sp1(lk.y, ls.y); p.k.y = a.k; p.s2.y = a.s2; p.r.y = a.r;
    a = sp1(lk.z, ls.z); p.k.z = a.k; p.s2.z = a.s2; p.r.z = a.r;
    a = sp1(lk.w, ls.w); p.k.w = a.k; p.s2.w = a.s2; p.r.w = a.r;
    p.mu = mu;
    return p;
}

// Exact OU transition coefficients (A = exp(-k dt); Q exact w/ Taylor fallback).
__device__ __forceinline__ C1 ou_coeff(float dt, float kappa, float s2, float r,
                                       float mu) {
    C1 o;
    float e = kappa * dt;
    o.A = __expf(-e);
    float two = 2.f * e;
    float Qe = r * (1.f - o.A * o.A);
    float Qt = s2 * dt * fmaf(two * two, (1.f / 6.f), 1.f - e);
    float Q = (two < 1e-6f) ? Qt : Qe;
    o.sQ = sqrtf(Q);
    o.bm = mu * (1.f - o.A);
    return o;
}

__device__ __forceinline__ C4 coeff4(float dt, const P4& p) {
    C4 c;
    C1 o;
    o = ou_coeff(dt, p.k.x, p.s2.x, p.r.x, p.mu.x); c.A.x = o.A; c.bm.x = o.bm; c.sQ.x = o.sQ;
    o = ou_coeff(dt, p.k.y, p.s2.y, p.r.y, p.mu.y); c.A.y = o.A; c.bm.y = o.bm; c.sQ.y = o.sQ;
    o = ou_coeff(dt, p.k.z, p.s2.z, p.r.z, p.mu.z); c.A.z = o.A; c.bm.z = o.bm; c.sQ.z = o.sQ;
    o = ou_coeff(dt, p.k.w, p.s2.w, p.r.w, p.mu.w); c.A.w = o.A; c.bm.w = o.bm; c.sQ.w = o.sQ;
    return c;
}

__device__ __forceinline__ f4 sqrt4(const f4 v) {
    f4 r;
    r.x = sqrtf(v.x); r.y = sqrtf(v.y); r.z = sqrtf(v.z); r.w = sqrtf(v.w);
    return r;
}

// -------------------- pass 1: segment partials (noise read #1) ------------
// Block (s,bg), wave w owns chain b = bg*4+w. NT-reads its noise segment
// (leaves L3 copy for pass 2 -- r12 PMC), writes packed (P,U) adjacent
// (one 128B line per scan hop).
__global__ __launch_bounds__(256) void ou_partials(
    const float* __restrict__ ts, const f4* __restrict__ noise4,
    const f4* __restrict__ mu4, const f4* __restrict__ lk4,
    const f4* __restrict__ ls4,
    f4* __restrict__ PU) {
    __shared__ float dts[LL];
    const int lane = threadIdx.x & 63;
    const int w = threadIdx.x >> 6;
    const int s = blockIdx.x / BPG;
    const int bg = blockIdx.x % BPG;
    const int b = bg * WPB + w;
    const int t0 = s * LL;

    if (threadIdx.x < LL) {
        int k = t0 + threadIdx.x;
        float dt = 1e-6f;
        if (k >= 1) dt = fmaxf(ts[k] - ts[k - 1], 1e-6f);
        dts[threadIdx.x] = dt;
    }
    __syncthreads();

    P4 p = load_params4(mu4, lk4, ls4, lane);
    const f4* np = noise4 + (size_t)b * TT * D4 + lane;

    f4 U = {0.f, 0.f, 0.f, 0.f};
    f4 P = {1.f, 1.f, 1.f, 1.f};
    int kstart = t0;
    if (s == 0) {
        f4 n0 = __builtin_nontemporal_load(np);
        U = n0 * sqrt4(p.r) + p.mu;   // true initial condition
        P = (f4){0.f, 0.f, 0.f, 0.f}; // absorbing: U is the actual state
        kstart = 1;
    }

    float dtprev = -1.f;
    C4 cc;
#pragma unroll 4
    for (int k = kstart; k < t0 + LL; ++k) {
        float dt = dts[k - t0];
        f4 n = __builtin_nontemporal_load(np + (size_t)k * D4);
        if (dt != dtprev) { cc = coeff4(dt, p); dtprev = dt; } // wave-uniform
        f4 cv = cc.sQ * n + cc.bm;
        U = cc.A * U + cv;
        P *= cc.A;
    }

    // packed publish: P and U adjacent (one cache line per hop in pass 2)
    size_t base = (((size_t)s * BB + b) * D4 + lane) * 2;
    PU[base] = P;
    PU[base + 1] = U;
}

// -------------------- pass 2: per-block scan + replay (noise read #2) ------
// Block (s,bg) issues the head of its noise stream FIRST (prefetch overlaps
// HBM latency with the scan's L2-latency chain), redundantly scans its
// columns' packed partials j=0..s-1 (L2-resident, independent-address
// loads), then replays its segment and plain-stores the output (no write
// amplification -- r12 PMC). Reversed-s: long-scan blocks dispatch first.
// No cross-block sync of any kind.
__global__ __launch_bounds__(256) void ou_scan_replay(
    const float* __restrict__ ts, const f4* __restrict__ noise4,
    const f4* __restrict__ mu4, const f4* __restrict__ lk4,
    const f4* __restrict__ ls4,
    const f4* __restrict__ PU, f4* __restrict__ out4) {
    __shared__ float dts[LL];
    const int lane = threadIdx.x & 63;
    const int w = threadIdx.x >> 6;
    const int s = (SS - 1) - (blockIdx.x / BPG);  // reversed: long scans first
    const int bg = blockIdx.x % BPG;
    const int b = bg * WPB + w;
    const int t0 = s * LL;

    if (threadIdx.x < LL) {
        int k = t0 + threadIdx.x;
        float dt = 1e-6f;
        if (k >= 1) dt = fmaxf(ts[k] - ts[k - 1], 1e-6f);
        dts[threadIdx.x] = dt;
    }
    __syncthreads();

    P4 p = load_params4(mu4, lk4, ls4, lane);
    const f4* np = noise4 + (size_t)b * TT * D4 + lane;
    f4* op = out4 + (size_t)b * TT * D4 + lane;

    // prefetch head of the noise stream before the scan (independent of it)
    f4 nbuf[PF];
#pragma unroll
    for (int i = 0; i < PF; ++i)
        nbuf[i] = __builtin_nontemporal_load(np + (size_t)(t0 + i) * D4);

    f4 y;
    if (s > 0) {
        // boundary scan over segments 0..s-1 (packed PU, L2-resident;
        // segment 0's P=0 absorbs, so uniform inc = P*inc + U from inc=0)
        f4 inc = {0.f, 0.f, 0.f, 0.f};
        const size_t lbase = (size_t)b * D4 + lane;
        const size_t stride = (size_t)BB * D4;
#pragma unroll 4
        for (int j = 0; j < s; ++j) {
            size_t base = (lbase + (size_t)j * stride) * 2;
            f4 Pv = PU[base];
            f4 Uv = PU[base + 1];
            inc = Pv * inc + Uv;
        }
        y = inc; // y at end of segment s-1 == start state for segment s
    }

    float dtprev = -1.f;
    C4 cc;
    int kstart = t0;
    if (s == 0) {
        y = nbuf[0] * sqrt4(p.r) + p.mu;
        op[0] = y;
        kstart = 1;
    }
#pragma unroll 4
    for (int k = kstart; k < t0 + LL; ++k) {
        int i = k - t0;
        float dt = dts[i];
        f4 n = (i < PF) ? nbuf[i]
                        : __builtin_nontemporal_load(np + (size_t)k * D4);
        if (dt != dtprev) { cc = coeff4(dt, p); dtprev = dt; } // wave-uniform
        f4 cv = cc.sQ * n + cc.bm;
        y = cc.A * y + cv;
        op[(size_t)k * D4] = y;   // plain store: no amplification (r12)
    }
}

// -------------------- last-resort fallback: plain per-chain scan ------------
__global__ __launch_bounds__(128) void ou_fallback(
    const float* __restrict__ ts, const float2* __restrict__ noise2,
    const float2* __restrict__ mu2, const float2* __restrict__ lk2,
    const float2* __restrict__ ls2, float2* __restrict__ out2) {
    __shared__ float dts[TT];
    const int tid = threadIdx.x;
    const int b = blockIdx.x;
    for (int i = tid; i < TT; i += 128) {
        float dt = 1e-6f;
        if (i >= 1) dt = fmaxf(ts[i] - ts[i - 1], 1e-6f);
        dts[i] = dt;
    }
    __syncthreads();

    float2 lk = lk2[tid], ls = ls2[tid], mu = mu2[tid];
    P1 px = sp1(lk.x, ls.x);
    P1 py = sp1(lk.y, ls.y);

    const float2* np = noise2 + (size_t)b * TT * 128 + tid;
    float2* op = out2 + (size_t)b * TT * 128 + tid;

    float2 n0 = np[0];
    float2 y;
    y.x = fmaf(n0.x, sqrtf(px.r), mu.x);
    y.y = fmaf(n0.y, sqrtf(py.r), mu.y);
    op[0] = y;

#pragma unroll 4
    for (int k = 1; k < TT; ++k) {
        float dt = dts[k];
        float2 n = np[(size_t)k * 128];
        C1 cx = ou_coeff(dt, px.k, px.s2, px.r, mu.x);
        C1 cy = ou_coeff(dt, py.k, py.s2, py.r, mu.y);
        y.x = fmaf(cx.A, y.x, fmaf(cx.sQ, n.x, cx.bm));
        y.y = fmaf(cy.A, y.y, fmaf(cy.sQ, n.y, cy.bm));
        op[(size_t)k * 128] = y;
    }
}

// -------------------- launch --------------------
extern "C" void kernel_launch(void* const* d_in, const int* in_sizes, int n_in,
                              void* d_out, int out_size, void* d_ws, size_t ws_size,
                              hipStream_t stream) {
    const float* ts = (const float*)d_in[0];
    const f4* noise4 = (const f4*)d_in[1];
    const f4* mu4 = (const f4*)d_in[2];
    const f4* lk4 = (const f4*)d_in[3];
    const f4* ls4 = (const f4*)d_in[4];
    f4* out4 = (f4*)d_out;

    const size_t need = (size_t)SS * BB * D4 * 2 * sizeof(f4);   // 8.4 MB
    if (ws_size >= need) {
        f4* PU = (f4*)d_ws;
        ou_partials<<<GRID, 256, 0, stream>>>(ts, noise4, mu4, lk4, ls4, PU);
        ou_scan_replay<<<GRID, 256, 0, stream>>>(ts, noise4, mu4, lk4, ls4,
                                                 PU, out4);
    } else {
        ou_fallback<<<BB, 128, 0, stream>>>(ts, (const float2*)d_in[1],
                                            (const float2*)d_in[2],
                                            (const float2*)d_in[3],
                                            (const float2*)d_in[4],
                                            (float2*)d_out);
    }
}

// Round 14
// 89.554 us; speedup vs baseline: 1.5146x; 1.2300x over previous
//
#include <hip/hip_runtime.h>
#include <math.h>

// Problem constants (from reference): B=64, T=2048, D=256
#define BB 64
#define TT 2048
#define D4 64             // D/4 -> one float4 per lane, one wave covers D
#define SS 64             // time segments
#define LL (TT / SS)      // 32 steps per segment
#define WPB 4             // waves per block (each wave owns one chain b)
#define BPG (BB / WPB)    // 16 b-groups
#define GRID (SS * BPG)   // 1024 blocks

// Native clang vector: elementwise ops, NT-store compatible.
typedef float f4 __attribute__((ext_vector_type(4)));

// -------------------- math helpers --------------------

__device__ __forceinline__ float softplus_f(float x) {
    // stable log1p(exp(x)) to match jax.nn.softplus
    return (x > 0.f) ? (x + log1pf(expf(-x))) : log1pf(expf(x));
}

struct P4 { f4 k, s2, r, mu; };   // per-lane params for 4 dims
struct C4 { f4 A, bm, sQ; };      // per-step coefficients
struct P1 { float k, s2, r; };
struct C1 { float A, bm, sQ; };

__device__ __forceinline__ P1 sp1(float lk, float ls) {
    P1 o;
    o.k = softplus_f(lk) + 1e-6f;
    float s = softplus_f(ls) + 1e-6f;
    o.s2 = s * s;
    o.r = o.s2 / fmaxf(2.f * o.k, 1e-12f);
    return o;
}

__device__ __forceinline__ P4 load_params4(const f4* __restrict__ mu4,
                                           const f4* __restrict__ lk4,
                                           const f4* __restrict__ ls4,
                                           int lane) {
    f4 lk = lk4[lane], ls = ls4[lane], mu = mu4[lane];
    P4 p;
    P1 a;
    a = sp1(lk.x, ls.x); p.k.x = a.k; p.s2.x = a.s2; p.r.x = a.r;
    a = sp1(lk.y, ls.y); p.k.y = a.k; p.s2.y = a.s2; p.r.y = a.r;
    a = sp1(lk.z, ls.z); p.k.z = a.k; p.s2.z = a.s2; p.r.z = a.r;
    a = sp1(lk.w, ls.w); p.k.w = a.k; p.s2.w = a.s2; p.r.w = a.r;
    p.mu = mu;
    return p;
}

// Exact OU transition coefficients (A = exp(-k dt); Q exact w/ Taylor fallback).
__device__ __forceinline__ C1 ou_coeff(float dt, float kappa, float s2, float r,
                                       float mu) {
    C1 o;
    float e = kappa * dt;
    o.A = __expf(-e);
    float two = 2.f * e;
    float Qe = r * (1.f - o.A * o.A);
    float Qt = s2 * dt * fmaf(two * two, (1.f / 6.f), 1.f - e);
    float Q = (two < 1e-6f) ? Qt : Qe;
    o.sQ = sqrtf(Q);
    o.bm = mu * (1.f - o.A);
    return o;
}

__device__ __forceinline__ C4 coeff4(float dt, const P4& p) {
    C4 c;
    C1 o;
    o = ou_coeff(dt, p.k.x, p.s2.x, p.r.x, p.mu.x); c.A.x = o.A; c.bm.x = o.bm; c.sQ.x = o.sQ;
    o = ou_coeff(dt, p.k.y, p.s2.y, p.r.y, p.mu.y); c.A.y = o.A; c.bm.y = o.bm; c.sQ.y = o.sQ;
    o = ou_coeff(dt, p.k.z, p.s2.z, p.r.z, p.mu.z); c.A.z = o.A; c.bm.z = o.bm; c.sQ.z = o.sQ;
    o = ou_coeff(dt, p.k.w, p.s2.w, p.r.w, p.mu.w); c.A.w = o.A; c.bm.w = o.bm; c.sQ.w = o.sQ;
    return c;
}

__device__ __forceinline__ f4 sqrt4(const f4 v) {
    f4 r;
    r.x = sqrtf(v.x); r.y = sqrtf(v.y); r.z = sqrtf(v.z); r.w = sqrtf(v.w);
    return r;
}

// -------------------- kernel A: segment partials (noise read #1) -----------
// Wave w of block owns chain b = bg*4+w, segment s. PLAIN noise loads
// (L2/L3-allocating: leaves residue for kernel B's re-read -- the r6 pairing;
// NT loads here cost p2 60->104 us, r13 PMC). Writes (P,U) partials.
__global__ __launch_bounds__(256) void ou_partials(
    const float* __restrict__ ts, const f4* __restrict__ noise4,
    const f4* __restrict__ mu4, const f4* __restrict__ lk4,
    const f4* __restrict__ ls4,
    f4* __restrict__ Pw, f4* __restrict__ Uw) {
    __shared__ float dts[LL];
    const int lane = threadIdx.x & 63;
    const int w = threadIdx.x >> 6;
    const int s = blockIdx.x / BPG;
    const int bg = blockIdx.x % BPG;
    const int b = bg * WPB + w;
    const int t0 = s * LL;

    if (threadIdx.x < LL) {
        int k = t0 + threadIdx.x;
        float dt = 1e-6f;
        if (k >= 1) dt = fmaxf(ts[k] - ts[k - 1], 1e-6f);
        dts[threadIdx.x] = dt;
    }
    __syncthreads();

    P4 p = load_params4(mu4, lk4, ls4, lane);
    const f4* np = noise4 + (size_t)b * TT * D4 + lane;

    f4 U = {0.f, 0.f, 0.f, 0.f};
    f4 P = {1.f, 1.f, 1.f, 1.f};
    int kstart = t0;
    if (s == 0) {
        f4 n0 = np[0];
        U = n0 * sqrt4(p.r) + p.mu;   // true initial condition
        P = (f4){0.f, 0.f, 0.f, 0.f}; // absorbing: U is the actual state
        kstart = 1;
    }

    float dtprev = -1.f;
    C4 cc;
#pragma unroll 4
    for (int k = kstart; k < t0 + LL; ++k) {
        float dt = dts[k - t0];
        f4 n = np[(size_t)k * D4];
        if (dt != dtprev) { cc = coeff4(dt, p); dtprev = dt; } // wave-uniform
        f4 cv = cc.sQ * n + cc.bm;
        U = cc.A * U + cv;
        P *= cc.A;
    }

    size_t idx = ((size_t)s * BB + b) * D4 + lane;
    Pw[idx] = P;
    Uw[idx] = U;
}

// -------------------- kernel B: per-block boundary scan + replay -----------
// Each block (s,b) computes its own segment-start state by scanning the
// L2/L3-resident partials of segments 0..s-1 (<=63 dependent f4-fmas; no
// cross-block sync of any kind), then replays its segment with PLAIN noise
// loads (L2/L3 residue from kernel A) and NT f4 stores for the output
// (streams out without polluting the caches; no write amplification at
// 16B/lane). Long scans get LOW blockIdx so they dispatch first.
__global__ __launch_bounds__(256) void ou_scan_replay(
    const float* __restrict__ ts, const f4* __restrict__ noise4,
    const f4* __restrict__ mu4, const f4* __restrict__ lk4,
    const f4* __restrict__ ls4,
    const f4* __restrict__ Pw, const f4* __restrict__ Uw,
    f4* __restrict__ out4) {
    __shared__ float dts[LL];
    const int lane = threadIdx.x & 63;
    const int w = threadIdx.x >> 6;
    const int s = (SS - 1) - (blockIdx.x / BPG);  // reversed: long scans first
    const int bg = blockIdx.x % BPG;
    const int b = bg * WPB + w;
    const int t0 = s * LL;

    if (threadIdx.x < LL) {
        int k = t0 + threadIdx.x;
        float dt = 1e-6f;
        if (k >= 1) dt = fmaxf(ts[k] - ts[k - 1], 1e-6f);
        dts[threadIdx.x] = dt;
    }
    __syncthreads();

    P4 p = load_params4(mu4, lk4, ls4, lane);
    const f4* np = noise4 + (size_t)b * TT * D4 + lane;
    f4* op = out4 + (size_t)b * TT * D4 + lane;

    f4 y;
    int kstart = t0;
    if (s == 0) {
        f4 n0 = np[0];
        y = n0 * sqrt4(p.r) + p.mu;
        __builtin_nontemporal_store(y, op);
        kstart = 1;
    } else {
        // boundary scan over segments 0..s-1 for this (b, lane) column.
        // Segment 0's (P,U) is absorbing (P=0, U=y_end), so inc starts at U_0.
        const size_t stride = (size_t)BB * D4;
        const size_t i0 = (size_t)b * D4 + lane;
        f4 inc = Uw[i0];
#pragma unroll 4
        for (int j = 1; j < s; ++j) {
            size_t idx = i0 + (size_t)j * stride;
            f4 Pv = Pw[idx];
            f4 Uv = Uw[idx];
            inc = Pv * inc + Uv;
        }
        y = inc; // y at end of segment s-1 == start state for segment s
    }

    float dtprev = -1.f;
    C4 cc;
#pragma unroll 4
    for (int k = kstart; k < t0 + LL; ++k) {
        float dt = dts[k - t0];
        f4 n = np[(size_t)k * D4];
        if (dt != dtprev) { cc = coeff4(dt, p); dtprev = dt; } // wave-uniform
        f4 cv = cc.sQ * n + cc.bm;
        y = cc.A * y + cv;
        // NT store: stream the output without evicting noise from L2/L3
        __builtin_nontemporal_store(y, op + (size_t)k * D4);
    }
}

// -------------------- last-resort fallback: plain per-chain scan ------------
__global__ __launch_bounds__(128) void ou_fallback(
    const float* __restrict__ ts, const float2* __restrict__ noise2,
    const float2* __restrict__ mu2, const float2* __restrict__ lk2,
    const float2* __restrict__ ls2, float2* __restrict__ out2) {
    __shared__ float dts[TT];
    const int tid = threadIdx.x;
    const int b = blockIdx.x;
    for (int i = tid; i < TT; i += 128) {
        float dt = 1e-6f;
        if (i >= 1) dt = fmaxf(ts[i] - ts[i - 1], 1e-6f);
        dts[i] = dt;
    }
    __syncthreads();

    float2 lk = lk2[tid], ls = ls2[tid], mu = mu2[tid];
    P1 px = sp1(lk.x, ls.x);
    P1 py = sp1(lk.y, ls.y);

    const float2* np = noise2 + (size_t)b * TT * 128 + tid;
    float2* op = out2 + (size_t)b * TT * 128 + tid;

    float2 n0 = np[0];
    float2 y;
    y.x = fmaf(n0.x, sqrtf(px.r), mu.x);
    y.y = fmaf(n0.y, sqrtf(py.r), mu.y);
    op[0] = y;

#pragma unroll 4
    for (int k = 1; k < TT; ++k) {
        float dt = dts[k];
        float2 n = np[(size_t)k * 128];
        C1 cx = ou_coeff(dt, px.k, px.s2, px.r, mu.x);
        C1 cy = ou_coeff(dt, py.k, py.s2, py.r, mu.y);
        y.x = fmaf(cx.A, y.x, fmaf(cx.sQ, n.x, cx.bm));
        y.y = fmaf(cy.A, y.y, fmaf(cy.sQ, n.y, cy.bm));
        op[(size_t)k * 128] = y;
    }
}

// -------------------- launch --------------------
extern "C" void kernel_launch(void* const* d_in, const int* in_sizes, int n_in,
                              void* d_out, int out_size, void* d_ws, size_t ws_size,
                              hipStream_t stream) {
    const float* ts = (const float*)d_in[0];
    const f4* noise4 = (const f4*)d_in[1];
    const f4* mu4 = (const f4*)d_in[2];
    const f4* lk4 = (const f4*)d_in[3];
    const f4* ls4 = (const f4*)d_in[4];
    f4* out4 = (f4*)d_out;

    const size_t seg = (size_t)SS * BB * D4; // f4 elements per ws buffer
    if (ws_size >= 2 * seg * sizeof(f4)) {
        f4* Pw = (f4*)d_ws;
        f4* Uw = Pw + seg;
        ou_partials<<<GRID, 256, 0, stream>>>(ts, noise4, mu4, lk4, ls4, Pw, Uw);
        ou_scan_replay<<<GRID, 256, 0, stream>>>(ts, noise4, mu4, lk4, ls4,
                                                 Pw, Uw, out4);
    } else {
        ou_fallback<<<BB, 128, 0, stream>>>(ts, (const float2*)d_in[1],
                                            (const float2*)d_in[2],
                                            (const float2*)d_in[3],
                                            (const float2*)d_in[4],
                                            (float2*)d_out);
    }
}